// Round 11
// baseline (62.106 us; speedup 1.0000x reference)
//
#include <hip/hip_runtime.h>
#include <hip/hip_fp16.h>
#include <math.h>

#define N_NODES 50000
#define K_NEI   32
#define D_FEAT  128
#define LEAKY   0.01f

#define NPG  3                         // nodes per 32-lane group
#define GPB  8                         // 32-lane groups per 256-thread block
#define NPB  (NPG * GPB)               // 24 nodes per block
#define GRID ((N_NODES + NPB - 1) / NPB)   // 2084 blocks ~ single generation @8/CU

#define CHUNK_SHIFT 12                 // 4096 rows = 1 MB f16 per chunk
#define NCHUNKS     ((N_NODES + (1 << CHUNK_SHIFT) - 1) >> CHUNK_SHIFT)   // 13

// ---------- Phase 1: g = feat.a_nei, h = feat.a_ref, fh = f16(feat) ----------
__global__ __launch_bounds__(256) void precompute_kernel(
    const float* __restrict__ feat,
    const float* __restrict__ att,
    unsigned short* __restrict__ fh,
    float* __restrict__ g,
    float* __restrict__ h)
{
    const int lane = threadIdx.x & 31;
    const int row  = blockIdx.x * 8 + (threadIdx.x >> 5);
    if (row >= N_NODES) return;

    const float4 a_ref = *(const float4*)&att[4 * lane];
    const float4 a_nei = *(const float4*)&att[D_FEAT + 4 * lane];
    const float4 f     = *(const float4*)&feat[(size_t)row * D_FEAT + 4 * lane];

    float sr = f.x * a_ref.x + f.y * a_ref.y + f.z * a_ref.z + f.w * a_ref.w;
    float sn = f.x * a_nei.x + f.y * a_nei.y + f.z * a_nei.z + f.w * a_nei.w;
    #pragma unroll
    for (int off = 16; off >= 1; off >>= 1) {
        sr += __shfl_xor(sr, off, 32);
        sn += __shfl_xor(sn, off, 32);
    }
    if (lane == 0) { h[row] = sr; g[row] = sn; }

    const __half2 p0 = __floats2half2_rn(f.x, f.y);
    const __half2 p1 = __floats2half2_rn(f.z, f.w);
    uint2 st;
    st.x = *(const unsigned*)&p0;
    st.y = *(const unsigned*)&p1;
    *(uint2*)&fh[(size_t)row * D_FEAT + 4 * lane] = st;
}

// ---------- Phase 2: LDS rank-sorted pairs, single-generation f16 gather -----
__global__ __launch_bounds__(256, 8) void gather_lds(
    const unsigned short* __restrict__ fh,
    const int*   __restrict__ nei,
    const float* __restrict__ g,
    const float* __restrict__ h,
    float*       __restrict__ out)
{
    // rank-major: pairs[grp][rank][j] = (idx, w) -> contiguous 24 B per rank
    __shared__ uint2 pairs[GPB][K_NEI][NPG];   // 6 KB

    const int lane       = threadIdx.x & 31;
    const int grp        = threadIdx.x >> 5;       // 0..7
    const int group      = blockIdx.x * GPB + grp;
    const int half_shift = threadIdx.x & 32;       // 0 lower half, 32 upper half
    const int node0      = group * NPG;
    const unsigned lt    = (1u << lane) - 1u;

    // ---- setup: weights + chunk-sort rank, scatter (idx,w) into LDS ----
    #pragma unroll
    for (int j = 0; j < NPG; ++j) {
        const int  node  = node0 + j;
        const bool valid = (node < N_NODES);

        const int idx = valid ? nei[node * K_NEI + lane] : 0;
        float sc = valid ? (h[node] + g[idx]) : 0.f;
        sc = (sc >= 0.f) ? sc : LEAKY * sc;
        const float p = __expf(sc);          // no-max softmax: |score| small, f32-safe
        float denom = p;
        #pragma unroll
        for (int off = 16; off >= 1; off >>= 1)
            denom += __shfl_xor(denom, off, 32);
        const float w = valid ? (p / denom) : 0.f;   // phantom node: weight 0

        const int cid = idx >> CHUNK_SHIFT;
        int rank = 0;
        #pragma unroll
        for (int c = 0; c < NCHUNKS; ++c) {
            const unsigned long long b = __ballot(cid == c);
            const unsigned bh = (unsigned)(b >> half_shift);
            rank += (c < cid)  ? __popc(bh)      : 0;
            rank += (c == cid) ? __popc(bh & lt) : 0;
        }
        pairs[grp][rank][j] = make_uint2((unsigned)idx, __float_as_uint(w));
    }
    __syncthreads();

    // ---- flat, divergence-free gather in (approx) chunk order ----
    float4 o0 = make_float4(0.f, 0.f, 0.f, 0.f);
    float4 o1 = make_float4(0.f, 0.f, 0.f, 0.f);
    float4 o2 = make_float4(0.f, 0.f, 0.f, 0.f);

    const unsigned lbyte = (unsigned)(lane << 3);  // byte offset of this lane's 8 B
    const char* fbase = (const char*)fh;

    #pragma unroll 4
    for (int i = 0; i < K_NEI; ++i) {
        const uint2 t0 = pairs[grp][i][0];
        const uint2 t1 = pairs[grp][i][1];
        const uint2 t2 = pairs[grp][i][2];
        const float w0 = __uint_as_float(t0.y);
        const float w1 = __uint_as_float(t1.y);
        const float w2 = __uint_as_float(t2.y);
        const uint2 v0 = *(const uint2*)(fbase + ((t0.x << 8) + lbyte));
        const uint2 v1 = *(const uint2*)(fbase + ((t1.x << 8) + lbyte));
        const uint2 v2 = *(const uint2*)(fbase + ((t2.x << 8) + lbyte));

        const __half2 a0 = *(const __half2*)&v0.x, a1 = *(const __half2*)&v0.y;
        const __half2 b0 = *(const __half2*)&v1.x, b1 = *(const __half2*)&v1.y;
        const __half2 c0 = *(const __half2*)&v2.x, c1 = *(const __half2*)&v2.y;

        o0.x += w0 * __half2float(a0.x);   // v_fma_mix_f32
        o0.y += w0 * __half2float(a0.y);
        o0.z += w0 * __half2float(a1.x);
        o0.w += w0 * __half2float(a1.y);
        o1.x += w1 * __half2float(b0.x);
        o1.y += w1 * __half2float(b0.y);
        o1.z += w1 * __half2float(b1.x);
        o1.w += w1 * __half2float(b1.y);
        o2.x += w2 * __half2float(c0.x);
        o2.y += w2 * __half2float(c0.y);
        o2.z += w2 * __half2float(c1.x);
        o2.w += w2 * __half2float(c1.y);
    }

    // ---- ELU + guarded store ----
    {
        float4 r;
        r.x = (o0.x > 0.f) ? o0.x : expm1f(o0.x);
        r.y = (o0.y > 0.f) ? o0.y : expm1f(o0.y);
        r.z = (o0.z > 0.f) ? o0.z : expm1f(o0.z);
        r.w = (o0.w > 0.f) ? o0.w : expm1f(o0.w);
        if (node0 + 0 < N_NODES)
            *(float4*)&out[(size_t)(node0 + 0) * D_FEAT + 4 * lane] = r;
        r.x = (o1.x > 0.f) ? o1.x : expm1f(o1.x);
        r.y = (o1.y > 0.f) ? o1.y : expm1f(o1.y);
        r.z = (o1.z > 0.f) ? o1.z : expm1f(o1.z);
        r.w = (o1.w > 0.f) ? o1.w : expm1f(o1.w);
        if (node0 + 1 < N_NODES)
            *(float4*)&out[(size_t)(node0 + 1) * D_FEAT + 4 * lane] = r;
        r.x = (o2.x > 0.f) ? o2.x : expm1f(o2.x);
        r.y = (o2.y > 0.f) ? o2.y : expm1f(o2.y);
        r.z = (o2.z > 0.f) ? o2.z : expm1f(o2.z);
        r.w = (o2.w > 0.f) ? o2.w : expm1f(o2.w);
        if (node0 + 2 < N_NODES)
            *(float4*)&out[(size_t)(node0 + 2) * D_FEAT + 4 * lane] = r;
    }
}

// ---------- Fallback (round-1 kernel) if workspace too small ----------
__global__ __launch_bounds__(256, 4) void feat_encoder_fallback(
    const float* __restrict__ feat,
    const int*   __restrict__ nei,
    const float* __restrict__ att,
    float*       __restrict__ out)
{
    const int lane = threadIdx.x & 31;
    const int node = blockIdx.x * 8 + (threadIdx.x >> 5);
    if (node >= N_NODES) return;

    const float4 a_ref = *(const float4*)&att[4 * lane];
    const float4 a_nei = *(const float4*)&att[D_FEAT + 4 * lane];

    const float4 f = *(const float4*)&feat[(size_t)node * D_FEAT + 4 * lane];
    float sref = f.x * a_ref.x + f.y * a_ref.y + f.z * a_ref.z + f.w * a_ref.w;
    #pragma unroll
    for (int off = 16; off >= 1; off >>= 1)
        sref += __shfl_xor(sref, off, 32);

    const int idx = nei[node * K_NEI + lane];
    float  s = 0.f;
    float4 o = {0.f, 0.f, 0.f, 0.f};
    #pragma unroll
    for (int k = 0; k < K_NEI; ++k) {
        const int nk = __shfl(idx, k, 32);
        const float4 v = *(const float4*)&feat[(size_t)nk * D_FEAT + 4 * lane];
        float partial = v.x * a_nei.x + v.y * a_nei.y + v.z * a_nei.z + v.w * a_nei.w;
        #pragma unroll
        for (int off = 16; off >= 1; off >>= 1)
            partial += __shfl_xor(partial, off, 32);
        float score = partial + sref;
        score = (score >= 0.f) ? score : LEAKY * score;
        const float p = __expf(score);
        s += p;
        o.x += p * v.x; o.y += p * v.y; o.z += p * v.z; o.w += p * v.w;
    }
    const float inv = 1.0f / s;
    float4 r;
    r.x = o.x * inv; r.y = o.y * inv; r.z = o.z * inv; r.w = o.w * inv;
    r.x = (r.x > 0.f) ? r.x : expm1f(r.x);
    r.y = (r.y > 0.f) ? r.y : expm1f(r.y);
    r.z = (r.z > 0.f) ? r.z : expm1f(r.z);
    r.w = (r.w > 0.f) ? r.w : expm1f(r.w);
    *(float4*)&out[(size_t)node * D_FEAT + 4 * lane] = r;
}

extern "C" void kernel_launch(void* const* d_in, const int* in_sizes, int n_in,
                              void* d_out, int out_size, void* d_ws, size_t ws_size,
                              hipStream_t stream) {
    const float* feat = (const float*)d_in[0];
    const int*   nei  = (const int*)d_in[1];
    const float* att  = (const float*)d_in[2];
    float*       out  = (float*)d_out;

    const size_t fh_bytes = (size_t)N_NODES * D_FEAT * sizeof(unsigned short); // 12.8 MB
    const size_t g_bytes  = (size_t)N_NODES * sizeof(float);                   // 200 KB
    const size_t need     = fh_bytes + 2 * g_bytes;

    if (ws_size >= need) {
        unsigned short* fh = (unsigned short*)d_ws;
        float* g = (float*)((char*)d_ws + fh_bytes);
        float* h = (float*)((char*)d_ws + fh_bytes + g_bytes);
        precompute_kernel<<<dim3((N_NODES + 7) / 8), 256, 0, stream>>>(feat, att, fh, g, h);
        gather_lds<<<dim3(GRID), 256, 0, stream>>>(fh, nei, g, h, out);
    } else {
        feat_encoder_fallback<<<dim3((N_NODES + 7) / 8), 256, 0, stream>>>(feat, nei, att, out);
    }
}